// Round 6
// baseline (219.833 us; speedup 1.0000x reference)
//
#include <hip/hip_runtime.h>
#include <hip/hip_bf16.h>

#define NSAMP 128
#define AGENTS 64
#define D 128
#define NN (NSAMP * AGENTS)      // 8192
#define LOG2E 1.44269504088896340736f
#define LN2   0.69314718055994530942f
#define EPSF  1e-5f

typedef __attribute__((ext_vector_type(8))) short short8;
typedef __attribute__((ext_vector_type(4))) float floatx4;

__device__ __forceinline__ float u2f(unsigned v) {
    float f; __builtin_memcpy(&f, &v, 4); return f;
}
__device__ __forceinline__ unsigned f2u(float f) {
    unsigned v; __builtin_memcpy(&v, &f, 4); return v;
}
__device__ __forceinline__ unsigned short f2bf(float f) {
    unsigned x; __builtin_memcpy(&x, &f, 4);
    return (unsigned short)((x + 0x7FFFu + ((x >> 16) & 1u)) >> 16);
}

// ---------------------------------------------------------------------------
// K0: convert x0 -> bf16 Xb; build transposed bf16 weights WT; zero stats acc.
//   WT[layer][arr][c][k] = Wside[k][c]; arr: 0=Af 1=Bf 2=As 3=Bs
// grid 577: 0..511 x-convert (8/thread), 512..575 weights, 576 zeros sacc.
// ---------------------------------------------------------------------------
__global__ __launch_bounds__(256) void cvt_kernel(
    const float* __restrict__ x0,
    const float* __restrict__ Wf1, const float* __restrict__ Ws1,
    const float* __restrict__ Wf2, const float* __restrict__ Ws2,
    unsigned short* __restrict__ Xb, unsigned short* __restrict__ WT,
    float* __restrict__ sacc)       // [2][2][128] zeroed
{
    int b = blockIdx.x;
    if (b < 512) {
        int off = (b * 256 + threadIdx.x) * 8;
        float4 v0 = *(const float4*)&x0[off];
        float4 v1 = *(const float4*)&x0[off + 4];
        short8 s;
        s[0] = (short)f2bf(v0.x); s[1] = (short)f2bf(v0.y);
        s[2] = (short)f2bf(v0.z); s[3] = (short)f2bf(v0.w);
        s[4] = (short)f2bf(v1.x); s[5] = (short)f2bf(v1.y);
        s[6] = (short)f2bf(v1.z); s[7] = (short)f2bf(v1.w);
        *(short8*)&Xb[off] = s;
    } else if (b < 576) {
        int wb = b - 512;                       // 0..63
        int rr = wb * 16 + (threadIdx.x >> 4);  // layer*512 + arr*128 + c
        int kk = (threadIdx.x & 15) * 8;
        int layer = rr >> 9, rem = rr & 511, arr = rem >> 7, c = rem & 127;
        const float* M = (arr < 2) ? (layer ? Wf2 : Wf1) : (layer ? Ws2 : Ws1);
        int side = arr & 1;                     // 0: W rows 0:128 (dst), 1: 128:256 (src)
        short8 s;
        #pragma unroll
        for (int j = 0; j < 8; ++j)
            s[j] = (short)f2bf(M[(size_t)(side * 128 + kk + j) * D + c]);
        *(short8*)&WT[(size_t)(layer * 4 + arr) * 16384 + c * 128 + kk] = s;
    } else {
        sacc[threadIdx.x]       = 0.f;
        sacc[256 + threadIdx.x] = 0.f;
    }
}

// ---------------------------------------------------------------------------
// K1: fused prep (MFMA) + edge aggregation. One block = (sample, 8 dst rows).
// grid 1024 = 128 samples x 8 groups; LDS exactly 40960 B -> 4 blocks/CU;
// __launch_bounds__(256,4) caps VGPR at 128 (code kept lean: W fragments
// reloaded from L2 per use, never hoisted).
// Phase A: MFMA gates -> LDS, packed bf16 pairs in u32 (low=f-gate, hi=s-gate).
//   EBpk: all 64 src rows;  EApk: the 16-row mtile containing our 8 dst rows.
//   Layouts (verified): A[m=lane&15][k=quad*8+j]; B[k][n=lane&15] from WT[n][k];
//   C/D col=lane&15, row=quad*4+reg.
// Phase B: agg[d][c] = sum_{j!=d} rcp(1+EAf*EBf)*log2(1+EAs*EBs)*ln2;
//   thread=(c,dh), 4 dst rows each; per-block stats -> atomicAdd into sacc.
// ---------------------------------------------------------------------------
__global__ __launch_bounds__(256, 4) void prep_edge(
    const unsigned short* __restrict__ Xb,   // [NN][128] bf16
    const unsigned short* __restrict__ WT,   // [4][128][128] bf16, this layer
    const float* __restrict__ centers,       // [NN][2]
    const float* __restrict__ Wf, const float* __restrict__ bf_,
    const float* __restrict__ Ws, const float* __restrict__ bs_,
    float* __restrict__ agg,                 // [NN][D] fp32
    float* __restrict__ sacc)                // [2][128] s1,s2
{
    const int s = blockIdx.x >> 3, g = blockIdx.x & 7;
    const int nbase = s * AGENTS;
    const int tid = threadIdx.x, wv = tid >> 6, lane = tid & 63;
    const int quad = lane >> 4, l16 = lane & 15;

    __shared__ unsigned int EBpk[64][128];   // 32 KB
    __shared__ unsigned int EApk[16][128];   // 8 KB  (mtile g>>1)

    // per-wave column metadata (2 ntiles)
    float cwf0[2], cwf1[2], cws0[2], cws1[2], bfv[2], bsv[2];
    #pragma unroll
    for (int p = 0; p < 2; ++p) {
        const int col = wv * 32 + p * 16 + l16;
        cwf0[p] = Wf[256 * D + col]; cwf1[p] = Wf[257 * D + col];
        cws0[p] = Ws[256 * D + col]; cws1[p] = Ws[257 * D + col];
        bfv[p] = bf_[col]; bsv[p] = bs_[col];
    }
    const int mg = g >> 1;

    for (int m = 0; m < 4; ++m) {
        short8 a[4];
        const unsigned short* xr = Xb + (size_t)(nbase + m * 16 + l16) * 128 + quad * 8;
        #pragma unroll
        for (int kc = 0; kc < 4; ++kc) a[kc] = *(const short8*)(xr + kc * 32);
        float ce0[4], ce1[4];
        #pragma unroll
        for (int r = 0; r < 4; ++r) {
            int n = nbase + m * 16 + quad * 4 + r;
            ce0[r] = centers[2 * n]; ce1[r] = centers[2 * n + 1];
        }
        #pragma unroll
        for (int p = 0; p < 2; ++p) {
            const int col = wv * 32 + p * 16 + l16;
            const unsigned short* w1 = WT + (size_t)1 * 16384 + (size_t)col * 128 + quad * 8;
            const unsigned short* w3 = WT + (size_t)3 * 16384 + (size_t)col * 128 + quad * 8;
            floatx4 aF = {0.f,0.f,0.f,0.f}, aS = {0.f,0.f,0.f,0.f};
            #pragma unroll
            for (int kc = 0; kc < 4; ++kc) {
                aF = __builtin_amdgcn_mfma_f32_16x16x32_bf16(a[kc], *(const short8*)(w1 + kc * 32), aF, 0,0,0);
                aS = __builtin_amdgcn_mfma_f32_16x16x32_bf16(a[kc], *(const short8*)(w3 + kc * 32), aS, 0,0,0);
            }
            #pragma unroll
            for (int r = 0; r < 4; ++r) {
                float ctf = fmaf(ce0[r], cwf0[p], ce1[r] * cwf1[p]);
                float cts = fmaf(ce0[r], cws0[p], ce1[r] * cws1[p]);
                unsigned uf = (unsigned)f2bf(__builtin_amdgcn_exp2f(-LOG2E * (aF[r] - ctf)));
                unsigned us = (unsigned)f2bf(__builtin_amdgcn_exp2f( LOG2E * (aS[r] - cts)));
                EBpk[m * 16 + quad * 4 + r][col] = uf | (us << 16);
            }
        }
        if (m == mg) {   // dst mtile: also compute EA gates (arrays 0,2)
            #pragma unroll
            for (int p = 0; p < 2; ++p) {
                const int col = wv * 32 + p * 16 + l16;
                const unsigned short* w0 = WT + (size_t)col * 128 + quad * 8;
                const unsigned short* w2 = WT + (size_t)2 * 16384 + (size_t)col * 128 + quad * 8;
                floatx4 aF = {0.f,0.f,0.f,0.f}, aS = {0.f,0.f,0.f,0.f};
                #pragma unroll
                for (int kc = 0; kc < 4; ++kc) {
                    aF = __builtin_amdgcn_mfma_f32_16x16x32_bf16(a[kc], *(const short8*)(w0 + kc * 32), aF, 0,0,0);
                    aS = __builtin_amdgcn_mfma_f32_16x16x32_bf16(a[kc], *(const short8*)(w2 + kc * 32), aS, 0,0,0);
                }
                #pragma unroll
                for (int r = 0; r < 4; ++r) {
                    float ctf = fmaf(ce0[r], cwf0[p], ce1[r] * cwf1[p]);
                    float cts = fmaf(ce0[r], cws0[p], ce1[r] * cws1[p]);
                    unsigned uf = (unsigned)f2bf(__builtin_amdgcn_exp2f(-LOG2E * (aF[r] + ctf + bfv[p])));
                    unsigned us = (unsigned)f2bf(__builtin_amdgcn_exp2f( LOG2E * (aS[r] + cts + bsv[p])));
                    EApk[quad * 4 + r][col] = uf | (us << 16);
                }
            }
        }
    }
    __syncthreads();

    // Phase B: thread = (c, dh); 4 dst rows each.
    const int c = tid & 127, dh = tid >> 7;
    const int r0 = (g & 1) * 8 + dh * 4;     // row within EApk's 16-row mtile
    float eaf[4], eas[4], acc[4];
    #pragma unroll
    for (int i = 0; i < 4; ++i) {
        unsigned pk = EApk[r0 + i][c];
        eaf[i] = u2f(pk << 16);
        eas[i] = u2f(pk & 0xFFFF0000u);
        acc[i] = 0.f;
    }
    #pragma unroll 2
    for (int j = 0; j < 64; ++j) {
        unsigned pk = EBpk[j][c];
        float ebf = u2f(pk << 16);
        float ebs = u2f(pk & 0xFFFF0000u);
        #pragma unroll
        for (int i = 0; i < 4; ++i) {
            float sg = __builtin_amdgcn_rcpf(fmaf(eaf[i], ebf, 1.f));
            float lg = __builtin_amdgcn_logf(fmaf(eas[i], ebs, 1.f));
            acc[i] = fmaf(sg, lg, acc[i]);
        }
    }
    float s1 = 0.f, s2 = 0.f;
    #pragma unroll
    for (int i = 0; i < 4; ++i) {
        int dl = g * 8 + dh * 4 + i;         // sample-local dst row 0..63
        unsigned pk = EBpk[dl][c];
        float ebf = u2f(pk << 16);
        float ebs = u2f(pk & 0xFFFF0000u);
        float sg = __builtin_amdgcn_rcpf(fmaf(eaf[i], ebf, 1.f));
        float lg = __builtin_amdgcn_logf(fmaf(eas[i], ebs, 1.f));
        float a = (acc[i] - sg * lg) * LN2;  // exact self-cancel (same inputs)
        agg[(size_t)(nbase + dl) * D + c] = a;
        s1 += a; s2 += a * a;
    }
    __syncthreads();                          // all LDS reads done; reuse EApk
    if (dh == 1) { EApk[0][c] = f2u(s1); EApk[1][c] = f2u(s2); }
    __syncthreads();
    if (dh == 0) {
        atomicAdd(&sacc[c],       s1 + u2f(EApk[0][c]));
        atomicAdd(&sacc[128 + c], s2 + u2f(EApk[1][c]));
    }
}

// ---------------------------------------------------------------------------
// K2: BN(+residual+relu) from raw sums; writes fp32 x1 and bf16 Xb. grid 512.
// ---------------------------------------------------------------------------
__global__ __launch_bounds__(256) void bncvt_kernel(
    const float* __restrict__ agg, const float* __restrict__ xin,
    const float* __restrict__ sacc,
    const float* __restrict__ gamma, const float* __restrict__ beta,
    float* __restrict__ x1, unsigned short* __restrict__ Xb)
{
    const int t = blockIdx.x * 256 + threadIdx.x;
    const int n = t >> 4;
    const int c = (t & 15) * 8;
    size_t off = (size_t)n * D + c;
    const float inv = 1.f / NN;
    float v[8]; short8 sv;
    #pragma unroll
    for (int h = 0; h < 2; ++h) {
        float4 a  = *(const float4*)&agg[off + h * 4];
        float4 xv = *(const float4*)&xin[off + h * 4];
        float4 s1 = *(const float4*)&sacc[c + h * 4];
        float4 s2 = *(const float4*)&sacc[128 + c + h * 4];
        float4 gm = *(const float4*)&gamma[c + h * 4];
        float4 bt = *(const float4*)&beta[c + h * 4];
        float mu, var, rs;
        mu = s1.x * inv; var = s2.x * inv - mu * mu; rs = rsqrtf(var + EPSF);
        v[h*4+0] = fmaxf(0.f, fmaf((a.x - mu) * rs, gm.x, bt.x) + xv.x);
        mu = s1.y * inv; var = s2.y * inv - mu * mu; rs = rsqrtf(var + EPSF);
        v[h*4+1] = fmaxf(0.f, fmaf((a.y - mu) * rs, gm.y, bt.y) + xv.y);
        mu = s1.z * inv; var = s2.z * inv - mu * mu; rs = rsqrtf(var + EPSF);
        v[h*4+2] = fmaxf(0.f, fmaf((a.z - mu) * rs, gm.z, bt.z) + xv.z);
        mu = s1.w * inv; var = s2.w * inv - mu * mu; rs = rsqrtf(var + EPSF);
        v[h*4+3] = fmaxf(0.f, fmaf((a.w - mu) * rs, gm.w, bt.w) + xv.w);
    }
    *(float4*)&x1[off]     = *(float4*)&v[0];
    *(float4*)&x1[off + 4] = *(float4*)&v[4];
    #pragma unroll
    for (int e = 0; e < 8; ++e) sv[e] = (short)f2bf(v[e]);
    *(short8*)&Xb[off] = sv;
}

// ---------------------------------------------------------------------------
// K3: final BN + residual + relu -> d_out (fp32), from raw sums. grid 512.
// ---------------------------------------------------------------------------
__global__ __launch_bounds__(256) void bn_kernel(
    const float* __restrict__ agg, const float* __restrict__ xin,
    const float* __restrict__ sacc,
    const float* __restrict__ gamma, const float* __restrict__ beta,
    float* __restrict__ outp)
{
    const int t = blockIdx.x * 256 + threadIdx.x;
    const int n = t >> 4;
    const int c = (t & 15) * 8;
    size_t off = (size_t)n * D + c;
    const float inv = 1.f / NN;
    float v[8];
    #pragma unroll
    for (int h = 0; h < 2; ++h) {
        float4 a  = *(const float4*)&agg[off + h * 4];
        float4 xv = *(const float4*)&xin[off + h * 4];
        float4 s1 = *(const float4*)&sacc[c + h * 4];
        float4 s2 = *(const float4*)&sacc[128 + c + h * 4];
        float4 gm = *(const float4*)&gamma[c + h * 4];
        float4 bt = *(const float4*)&beta[c + h * 4];
        float mu, var, rs;
        mu = s1.x * inv; var = s2.x * inv - mu * mu; rs = rsqrtf(var + EPSF);
        v[h*4+0] = fmaxf(0.f, fmaf((a.x - mu) * rs, gm.x, bt.x) + xv.x);
        mu = s1.y * inv; var = s2.y * inv - mu * mu; rs = rsqrtf(var + EPSF);
        v[h*4+1] = fmaxf(0.f, fmaf((a.y - mu) * rs, gm.y, bt.y) + xv.y);
        mu = s1.z * inv; var = s2.z * inv - mu * mu; rs = rsqrtf(var + EPSF);
        v[h*4+2] = fmaxf(0.f, fmaf((a.z - mu) * rs, gm.z, bt.z) + xv.z);
        mu = s1.w * inv; var = s2.w * inv - mu * mu; rs = rsqrtf(var + EPSF);
        v[h*4+3] = fmaxf(0.f, fmaf((a.w - mu) * rs, gm.w, bt.w) + xv.w);
    }
    *(float4*)&outp[off]     = *(float4*)&v[0];
    *(float4*)&outp[off + 4] = *(float4*)&v[4];
}

// ---------------------------------------------------------------------------
extern "C" void kernel_launch(void* const* d_in, const int* in_sizes, int n_in,
                              void* d_out, int out_size, void* d_ws, size_t ws_size,
                              hipStream_t stream) {
    const float* x0      = (const float*)d_in[0];
    const float* centers = (const float*)d_in[1];
    // d_in[2], d_in[3]: edge lists — clique structure is deterministic, unused.
    const float* Wf[2] = { (const float*)d_in[4],  (const float*)d_in[10] };
    const float* bf[2] = { (const float*)d_in[5],  (const float*)d_in[11] };
    const float* Ws[2] = { (const float*)d_in[6],  (const float*)d_in[12] };
    const float* bs[2] = { (const float*)d_in[7],  (const float*)d_in[13] };
    const float* gm[2] = { (const float*)d_in[8],  (const float*)d_in[14] };
    const float* bt[2] = { (const float*)d_in[9],  (const float*)d_in[15] };

    const size_t ND = (size_t)NN * D;              // 1048576
    unsigned short* ws_u = (unsigned short*)d_ws;
    unsigned short* Xb = ws_u;                     // ND bf16
    unsigned short* WT = ws_u + ND;                // 2 x 65536 bf16
    float* fbase = (float*)(WT + 2 * 65536);       // 16B-aligned
    float* agg   = fbase;                          // ND
    float* x1    = fbase + ND;                     // ND
    float* sacc  = fbase + 2 * ND;                 // 2 layers x 256

    float* outp = (float*)d_out;

    cvt_kernel<<<dim3(577), dim3(256), 0, stream>>>(
        x0, Wf[0], Ws[0], Wf[1], Ws[1], Xb, WT, sacc);

    // Layer 1
    prep_edge<<<dim3(1024), dim3(256), 0, stream>>>(
        Xb, WT, centers, Wf[0], bf[0], Ws[0], bs[0], agg, sacc);
    bncvt_kernel<<<dim3(512), dim3(256), 0, stream>>>(
        agg, x0, sacc, gm[0], bt[0], x1, Xb);

    // Layer 2
    prep_edge<<<dim3(1024), dim3(256), 0, stream>>>(
        Xb, WT + 65536, centers, Wf[1], bf[1], Ws[1], bs[1], agg, sacc + 256);
    bn_kernel<<<dim3(512), dim3(256), 0, stream>>>(
        agg, x1, sacc + 256, gm[1], bt[1], outp);
}

// Round 7
// 148.236 us; speedup vs baseline: 1.4830x; 1.4830x over previous
//
#include <hip/hip_runtime.h>
#include <hip/hip_bf16.h>

#define NSAMP 128
#define AGENTS 64
#define D 128
#define NN (NSAMP * AGENTS)      // 8192
#define LOG2E 1.44269504088896340736f
#define LN2   0.69314718055994530942f
#define EPSF  1e-5f

typedef __attribute__((ext_vector_type(8))) short short8;
typedef __attribute__((ext_vector_type(4))) float floatx4;

__device__ __forceinline__ float u2f(unsigned v) {
    float f; __builtin_memcpy(&f, &v, 4); return f;
}
__device__ __forceinline__ unsigned f2u(float f) {
    unsigned v; __builtin_memcpy(&v, &f, 4); return v;
}
__device__ __forceinline__ unsigned short f2bf(float f) {
    unsigned x; __builtin_memcpy(&x, &f, 4);
    return (unsigned short)((x + 0x7FFFu + ((x >> 16) & 1u)) >> 16);
}

// ---------------------------------------------------------------------------
// K0: build transposed bf16 weights WT[layer][arr][c][k] = Wside[k][c];
//     arr: 0=Af(dst) 1=Bf(src) 2=As(dst) 3=Bs(src).  Zero sacc (both layers).
// grid 65: 0..63 weights, 64 zeros sacc.
// ---------------------------------------------------------------------------
__global__ __launch_bounds__(256) void cvt_kernel(
    const float* __restrict__ Wf1, const float* __restrict__ Ws1,
    const float* __restrict__ Wf2, const float* __restrict__ Ws2,
    unsigned short* __restrict__ WT, float* __restrict__ sacc)
{
    int b = blockIdx.x;
    if (b < 64) {
        int rr = b * 16 + (threadIdx.x >> 4);   // layer*512 + arr*128 + c
        int kk = (threadIdx.x & 15) * 8;
        int layer = rr >> 9, rem = rr & 511, arr = rem >> 7, c = rem & 127;
        const float* M = (arr < 2) ? (layer ? Wf2 : Wf1) : (layer ? Ws2 : Ws1);
        int side = arr & 1;                     // 0: W rows 0:128 (dst), 1: 128:256 (src)
        short8 s;
        #pragma unroll
        for (int j = 0; j < 8; ++j)
            s[j] = (short)f2bf(M[(size_t)(side * 128 + kk + j) * D + c]);
        *(short8*)&WT[(size_t)(layer * 4 + arr) * 16384 + c * 128 + kk] = s;
    } else {
        sacc[threadIdx.x]       = 0.f;
        sacc[256 + threadIdx.x] = 0.f;
    }
}

// ---------------------------------------------------------------------------
// K1: fused prep (MFMA) + edge aggregation, channel-sliced (ZERO redundancy).
// Block = (sample s, 16-channel slice q); grid 1024 = 128 x 8; 4 blocks/CU.
// Phase A: wave w computes mtile w (16 rows) x this block's 16 cols x all 4
//   gate arrays; gates exp2'd and packed bf16-pairs into LDS:
//     EApk[row][cl] = EAf | EAs<<16   (dst gates, +bias, +center term)
//     EBpk[row][cl] = EBf | EBs<<16   (src gates, -center term)
//   A-frags converted fp32->bf16 in-register (no Xb array needed).
//   Layouts (verified): A[m=lane&15][k=quad*8+j]; B[k][n=lane&15] from WT[n][k];
//   C/D col=lane&15, row=quad*4+reg.
// Phase B: thread=(cl,slot): 4 dst rows each, j-loop over all 64 src rows:
//   agg[d][c] = sum_{j!=d} rcp(1+EAf*EBf)*log2(1+EAs*EBs)*ln2.
// Stats: slot-tree reduce in LDS, slot==0 atomicAdd into sacc.
// ---------------------------------------------------------------------------
__global__ __launch_bounds__(256, 4) void prep_edge(
    const float* __restrict__ xin,           // [NN][128] fp32
    const unsigned short* __restrict__ WT,   // [4][128][128] bf16, this layer
    const float* __restrict__ centers,       // [NN][2]
    const float* __restrict__ Wf, const float* __restrict__ bf_,
    const float* __restrict__ Ws, const float* __restrict__ bs_,
    float* __restrict__ agg,                 // [NN][D] fp32
    float* __restrict__ sacc)                // [2][128] s1,s2
{
    const int s = blockIdx.x >> 3, q = blockIdx.x & 7;
    const int nbase = s * AGENTS;
    const int tid = threadIdx.x, w = tid >> 6, lane = tid & 63;
    const int quad = lane >> 4, l16 = lane & 15;

    __shared__ unsigned int EApk[64][17];    // stride 17: conflict-light
    __shared__ unsigned int EBpk[64][17];

    // ---- Phase A ----
    const int col = q * 16 + l16;
    short8 a[4];
    {
        const float* xr = xin + (size_t)(nbase + w * 16 + l16) * D + quad * 8;
        #pragma unroll
        for (int kc = 0; kc < 4; ++kc) {
            float4 v0 = *(const float4*)(xr + kc * 32);
            float4 v1 = *(const float4*)(xr + kc * 32 + 4);
            short8 t;
            t[0] = (short)f2bf(v0.x); t[1] = (short)f2bf(v0.y);
            t[2] = (short)f2bf(v0.z); t[3] = (short)f2bf(v0.w);
            t[4] = (short)f2bf(v1.x); t[5] = (short)f2bf(v1.y);
            t[6] = (short)f2bf(v1.z); t[7] = (short)f2bf(v1.w);
            a[kc] = t;
        }
    }
    floatx4 acc[4];
    #pragma unroll
    for (int arr = 0; arr < 4; ++arr) {
        const unsigned short* wp = WT + ((size_t)arr * 128 + col) * 128 + quad * 8;
        floatx4 ac = {0.f, 0.f, 0.f, 0.f};
        #pragma unroll
        for (int kc = 0; kc < 4; ++kc)
            ac = __builtin_amdgcn_mfma_f32_16x16x32_bf16(
                a[kc], *(const short8*)(wp + kc * 32), ac, 0, 0, 0);
        acc[arr] = ac;
    }
    const float cwf0 = Wf[256 * D + col], cwf1 = Wf[257 * D + col];
    const float cws0 = Ws[256 * D + col], cws1 = Ws[257 * D + col];
    const float bfv = bf_[col], bsv = bs_[col];
    #pragma unroll
    for (int r = 0; r < 4; ++r) {
        int row = w * 16 + quad * 4 + r;
        int n = nbase + row;
        float ce0 = centers[2 * n], ce1 = centers[2 * n + 1];
        float ctf = fmaf(ce0, cwf0, ce1 * cwf1);
        float cts = fmaf(ce0, cws0, ce1 * cws1);
        unsigned eaf = (unsigned)f2bf(__builtin_amdgcn_exp2f(-LOG2E * (acc[0][r] + ctf + bfv)));
        unsigned eas = (unsigned)f2bf(__builtin_amdgcn_exp2f( LOG2E * (acc[2][r] + cts + bsv)));
        unsigned ebf = (unsigned)f2bf(__builtin_amdgcn_exp2f(-LOG2E * (acc[1][r] - ctf)));
        unsigned ebs = (unsigned)f2bf(__builtin_amdgcn_exp2f( LOG2E * (acc[3][r] - cts)));
        EApk[row][l16] = eaf | (eas << 16);
        EBpk[row][l16] = ebf | (ebs << 16);
    }
    __syncthreads();

    // ---- Phase B ----
    const int cl = tid & 15, slot = tid >> 4;   // 16 cl x 16 slots
    const int c = q * 16 + cl;
    float eaf[4], eas[4], ac2[4];
    #pragma unroll
    for (int i = 0; i < 4; ++i) {
        unsigned pk = EApk[slot * 4 + i][cl];
        eaf[i] = u2f(pk << 16);
        eas[i] = u2f(pk & 0xFFFF0000u);
        ac2[i] = 0.f;
    }
    #pragma unroll 4
    for (int j = 0; j < 64; ++j) {
        unsigned pk = EBpk[j][cl];
        float ebf = u2f(pk << 16);
        float ebs = u2f(pk & 0xFFFF0000u);
        #pragma unroll
        for (int i = 0; i < 4; ++i) {
            float sg = __builtin_amdgcn_rcpf(fmaf(eaf[i], ebf, 1.f));
            float lg = __builtin_amdgcn_logf(fmaf(eas[i], ebs, 1.f));
            ac2[i] = fmaf(sg, lg, ac2[i]);
        }
    }
    float s1 = 0.f, s2 = 0.f;
    #pragma unroll
    for (int i = 0; i < 4; ++i) {
        int d = slot * 4 + i;
        unsigned pk = EBpk[d][cl];
        float ebf = u2f(pk << 16);
        float ebs = u2f(pk & 0xFFFF0000u);
        float sg = __builtin_amdgcn_rcpf(fmaf(eaf[i], ebf, 1.f));
        float lg = __builtin_amdgcn_logf(fmaf(eas[i], ebs, 1.f));
        float v = (ac2[i] - sg * lg) * LN2;   // exact self-cancel (same inputs)
        agg[(size_t)(nbase + d) * D + c] = v;
        s1 += v; s2 += v * v;
    }
    __syncthreads();                           // all gate reads done; reuse LDS
    EApk[slot][cl] = f2u(s1);
    EBpk[slot][cl] = f2u(s2);
    __syncthreads();
    #pragma unroll
    for (int off = 8; off >= 1; off >>= 1) {
        if (slot < off) {
            EApk[slot][cl] = f2u(u2f(EApk[slot][cl]) + u2f(EApk[slot + off][cl]));
            EBpk[slot][cl] = f2u(u2f(EBpk[slot][cl]) + u2f(EBpk[slot + off][cl]));
        }
        __syncthreads();
    }
    if (slot == 0) {
        atomicAdd(&sacc[c],       u2f(EApk[0][cl]));
        atomicAdd(&sacc[128 + c], u2f(EBpk[0][cl]));
    }
}

// ---------------------------------------------------------------------------
// K2: BN + residual + relu from raw sums -> fp32 out. grid 512, 8 elems/thr.
// Used for both layers (layer1 -> x1, layer2 -> d_out).
// ---------------------------------------------------------------------------
__global__ __launch_bounds__(256) void bn_kernel(
    const float* __restrict__ agg, const float* __restrict__ xin,
    const float* __restrict__ sacc,
    const float* __restrict__ gamma, const float* __restrict__ beta,
    float* __restrict__ outp)
{
    const int t = blockIdx.x * 256 + threadIdx.x;
    const int n = t >> 4;
    const int c = (t & 15) * 8;
    size_t off = (size_t)n * D + c;
    const float inv = 1.f / NN;
    float v[8];
    #pragma unroll
    for (int h = 0; h < 2; ++h) {
        float4 a  = *(const float4*)&agg[off + h * 4];
        float4 xv = *(const float4*)&xin[off + h * 4];
        float4 s1 = *(const float4*)&sacc[c + h * 4];
        float4 s2 = *(const float4*)&sacc[128 + c + h * 4];
        float4 gm = *(const float4*)&gamma[c + h * 4];
        float4 bt = *(const float4*)&beta[c + h * 4];
        float mu, var, rs;
        mu = s1.x * inv; var = s2.x * inv - mu * mu; rs = rsqrtf(var + EPSF);
        v[h*4+0] = fmaxf(0.f, fmaf((a.x - mu) * rs, gm.x, bt.x) + xv.x);
        mu = s1.y * inv; var = s2.y * inv - mu * mu; rs = rsqrtf(var + EPSF);
        v[h*4+1] = fmaxf(0.f, fmaf((a.y - mu) * rs, gm.y, bt.y) + xv.y);
        mu = s1.z * inv; var = s2.z * inv - mu * mu; rs = rsqrtf(var + EPSF);
        v[h*4+2] = fmaxf(0.f, fmaf((a.z - mu) * rs, gm.z, bt.z) + xv.z);
        mu = s1.w * inv; var = s2.w * inv - mu * mu; rs = rsqrtf(var + EPSF);
        v[h*4+3] = fmaxf(0.f, fmaf((a.w - mu) * rs, gm.w, bt.w) + xv.w);
    }
    *(float4*)&outp[off]     = *(float4*)&v[0];
    *(float4*)&outp[off + 4] = *(float4*)&v[4];
}

// ---------------------------------------------------------------------------
extern "C" void kernel_launch(void* const* d_in, const int* in_sizes, int n_in,
                              void* d_out, int out_size, void* d_ws, size_t ws_size,
                              hipStream_t stream) {
    const float* x0      = (const float*)d_in[0];
    const float* centers = (const float*)d_in[1];
    // d_in[2], d_in[3]: edge lists — clique structure is deterministic, unused.
    const float* Wf[2] = { (const float*)d_in[4],  (const float*)d_in[10] };
    const float* bf[2] = { (const float*)d_in[5],  (const float*)d_in[11] };
    const float* Ws[2] = { (const float*)d_in[6],  (const float*)d_in[12] };
    const float* bs[2] = { (const float*)d_in[7],  (const float*)d_in[13] };
    const float* gm[2] = { (const float*)d_in[8],  (const float*)d_in[14] };
    const float* bt[2] = { (const float*)d_in[9],  (const float*)d_in[15] };

    const size_t ND = (size_t)NN * D;              // 1048576
    unsigned short* ws_u = (unsigned short*)d_ws;
    unsigned short* WT = ws_u;                     // 2 x 65536 bf16
    float* fbase = (float*)(WT + 2 * 65536);       // 16B-aligned
    float* agg   = fbase;                          // ND
    float* x1    = fbase + ND;                     // ND
    float* sacc  = fbase + 2 * ND;                 // 2 layers x 256

    float* outp = (float*)d_out;

    cvt_kernel<<<dim3(65), dim3(256), 0, stream>>>(
        Wf[0], Ws[0], Wf[1], Ws[1], WT, sacc);

    // Layer 1
    prep_edge<<<dim3(1024), dim3(256), 0, stream>>>(
        x0, WT, centers, Wf[0], bf[0], Ws[0], bs[0], agg, sacc);
    bn_kernel<<<dim3(512), dim3(256), 0, stream>>>(
        agg, x0, sacc, gm[0], bt[0], x1);

    // Layer 2
    prep_edge<<<dim3(1024), dim3(256), 0, stream>>>(
        x1, WT + 65536, centers, Wf[1], bf[1], Ws[1], bs[1], agg, sacc + 256);
    bn_kernel<<<dim3(512), dim3(256), 0, stream>>>(
        agg, x1, sacc + 256, gm[1], bt[1], outp);
}